// Round 3
// baseline (115.085 us; speedup 1.0000x reference)
//
#include <hip/hip_runtime.h>
#include <hip/hip_bf16.h>

// MPNN fused pipeline, R15b: resubmission of R15 (container failed with no
// diagnostics; kernel audited for OOB/deadlock/race — none found; suspect
// infra flake).  R14 reassociation + 128x128-tile double-buffered GEMM core
// (T3 "minimum 2-phase" prefetch, one vmcnt(0)+barrier per K-step).
//  - gemm128 (BM=BN=128, BK=64, 4 waves 2x2, 2x32KB LDS dbuf) replaces the
//    64x64 single-buffered gemm_bias_relu/gemm_nt_red: staged DMA traffic
//    226 MB -> 123 MB, each dispatch one grid round, DMA hides under MFMA.
//  - modes: 0 = fp32 bias+relu store (final GEMM)
//           1 = dual bf16 store: h cols (swz) + transposed et (swz)  (e-GEMM)
//           2 = scaled fp32 atomicAdd (split-K nt_red, M zeroed by prep)
//  - per-output-element accumulation order unchanged -> bit-identical to R14
//    (absmax must stay exactly 0.5).
// prep_all and gemm_small_n unchanged from R14.

typedef short bf16x8  __attribute__((ext_vector_type(8)));
typedef short short4v __attribute__((ext_vector_type(4)));
typedef float f32x4   __attribute__((ext_vector_type(4)));

__device__ inline short f2bf(float x) {                // fp32 -> bf16 RNE
    unsigned u = __builtin_bit_cast(unsigned, x);
    return (short)((u + 0x7fffu + ((u >> 16) & 1u)) >> 16);
}
__device__ inline float bf2f(short b) {
    return __builtin_bit_cast(float, (unsigned)((unsigned short)b) << 16);
}
__device__ inline void cp16_async(const char* g, char* l) {
    __builtin_amdgcn_global_load_lds(
        (const __attribute__((address_space(1))) unsigned int*)g,
        (__attribute__((address_space(3))) unsigned int*)l, 16, 0, 0);
}

// ------------------------------------------------------------------ prep_all
// grid (256,10), block (32,8):
//   y<8    : edge_x fp32 -> bf16 h[:,0:256] (swizzled) + Xt [256][8192] (swizzled).
//   y>=8   : tw<64   -> W1 tile  -> Wt1   (swizzled [n][k], ld 256)
//            tw<128  -> W2 tile  -> Wt2
//            tw<320  -> Wo tile  -> rows 0:256   -> Bt4[:,0:256]  (ld 768)
//                                   rows 256:768 -> Wtoh[:,0:512] (ld 512)
//            tw>=320 -> zero M (2*256*256 fp32) for gemm128 mode-2 atomics.
__global__ void prep_all(const float* __restrict__ X, short* __restrict__ h,
                         int ldh, short* __restrict__ Xt,
                         const float* __restrict__ W1, const float* __restrict__ W2,
                         const float* __restrict__ Wo,
                         short* __restrict__ Wt1, short* __restrict__ Wt2,
                         short* __restrict__ Wtoh, short* __restrict__ Bt4,
                         float* __restrict__ M)
{
    __shared__ short tile[32][33];
    const int tx = threadIdx.x, ty = threadIdx.y;      // 32 x 8
    if (blockIdx.y < 8) {
        const int r0 = blockIdx.x * 32, c0 = blockIdx.y * 32;
        #pragma unroll
        for (int i = 0; i < 4; ++i) {
            int row = ty + i * 8;
            short b = f2bf(X[(size_t)(r0 + row) * 256 + c0 + tx]);
            tile[row][tx] = b;
            int slot = ((((c0 & 32) + tx) >> 3) ^ ((r0 + row) & 7));
            h[(size_t)(r0 + row) * ldh + (c0 & ~63) + slot * 8 + (tx & 7)] = b;
        }
        __syncthreads();
        #pragma unroll
        for (int i = 0; i < 4; ++i) {
            int row = ty + i * 8;                      // d-local
            int d = c0 + row;
            int slot = ((((r0 & 32) + tx) >> 3) ^ (d & 7));
            Xt[(size_t)d * 8192 + (r0 & ~63) + slot * 8 + (tx & 7)] = tile[tx][row];
        }
    } else {
        int tw = (blockIdx.y - 8) * 256 + blockIdx.x;
        if (tw >= 320) {                               // zero M with idle blocks
            int i0 = (tw - 320) * 256 + ty * 32 + tx;
            for (int i = i0; i < 131072; i += 49152) M[i] = 0.f;
            return;
        }
        const float* src; short* dst; int ldwt, dk0, kx, ny;
        if (tw < 64)       { src = W1; dst = Wt1; ldwt = 256;
                             kx = tw >> 3; ny = tw & 7; dk0 = kx * 32; }
        else if (tw < 128) { int u = tw - 64; src = W2; dst = Wt2; ldwt = 256;
                             kx = u >> 3; ny = u & 7; dk0 = kx * 32; }
        else               { int u = tw - 128; int g = u >> 6; int rem = u & 63;
                             kx = rem >> 3; ny = rem & 7;
                             src = Wo + (size_t)g * 256 * 256;
                             if (g == 0) { dst = Bt4;  ldwt = 768; dk0 = kx * 32; }
                             else        { dst = Wtoh; ldwt = 512;
                                           dk0 = (g - 1) * 256 + kx * 32; } }
        const int k0l = kx * 32, n0 = ny * 32;
        #pragma unroll
        for (int i = 0; i < 4; ++i) {
            int row = ty + i * 8;
            tile[row][tx] = f2bf(src[(size_t)(k0l + row) * 256 + n0 + tx]);
        }
        __syncthreads();
        #pragma unroll
        for (int i = 0; i < 4; ++i) {
            int row = ty + i * 8;
            int n = n0 + row;
            int slot = ((((dk0 & 32) + tx) >> 3) ^ (n & 7));
            dst[(size_t)n * ldwt + (dk0 & ~63) + slot * 8 + (tx & 7)] = tile[tx][row];
        }
    }
}

// ------------------------------------------------------------------ gemm128
// C[128m x 128n] = sum_k A[m,k]*Bt[n,k], A/Bt bf16 granule-swizzled per
// 64-col k-block.  Double-buffered DMA staging: stage(t+1) issued before
// compute(t); single __syncthreads (vmcnt0+lgkm0 drain) per K-step.
// mode 0: fp32 out = relu(acc+bias), ld 256.
// mode 1: e = relu(acc+bias) -> hout cols cb (swz) + et[n][8192] (swz, via Ts).
// mode 2: atomicAdd(out + sim*65536, acc*scale); z = split*2+sim, Kwin=512.
__global__ __launch_bounds__(256, 1)
void gemm128(const short* __restrict__ A0, const short* __restrict__ A1, int lda,
             const short* __restrict__ B0, const short* __restrict__ B1, int ldb,
             int K,
             const float* __restrict__ bias0, const float* __restrict__ bias1,
             void* __restrict__ out0, void* __restrict__ out1,
             short* __restrict__ hout, int ldh,
             int mode, float scale)
{
    int z = blockIdx.z, sim, kbeg, kend;
    if (mode == 2) { sim = z & 1; kbeg = (z >> 1) * 512; kend = kbeg + 512; }
    else           { sim = z;     kbeg = 0;              kend = K; }
    const short* Ap   = sim ? A1 : A0;
    const short* Bp   = sim ? B1 : B0;
    const float* bias = sim ? bias1 : bias0;

    const int m0 = blockIdx.x * 128, n0 = blockIdx.y * 128;
    const int t = threadIdx.x;
    const int w = t >> 6, l = t & 63, lr = l & 15, q = l >> 4;
    const int wm = w >> 1, wn = w & 1;         // wave quadrant (2x2)
    const int wub = t & ~63;                   // wave-uniform thread base

    __shared__ __attribute__((aligned(16))) short S[2][2][128 * 64]; // 64 KB

    f32x4 acc[4][4];
    #pragma unroll
    for (int i = 0; i < 4; ++i)
        #pragma unroll
        for (int j = 0; j < 4; ++j) acc[i][j] = f32x4{0.f, 0.f, 0.f, 0.f};

    auto stage = [&](int buf, int k0) {
        #pragma unroll
        for (int it = 0; it < 4; ++it) {       // A: 128 rows x 8 granules
            int idx = it * 256 + t;
            int r = idx >> 3, s = idx & 7;
            cp16_async((const char*)(Ap + (size_t)(m0 + r) * lda + k0) + s * 16,
                       (char*)&S[buf][0][0] + (size_t)(it * 256 + wub) * 16);
        }
        #pragma unroll
        for (int it = 0; it < 4; ++it) {       // B: 128 rows x 8 granules
            int idx = it * 256 + t;
            int r = idx >> 3, s = idx & 7;
            cp16_async((const char*)(Bp + (size_t)(n0 + r) * ldb + k0) + s * 16,
                       (char*)&S[buf][1][0] + (size_t)(it * 256 + wub) * 16);
        }
    };

    stage(0, kbeg);
    __syncthreads();                           // full drain: buf0 ready
    int cur = 0;
    for (int k0 = kbeg; k0 < kend; k0 += 64) {
        if (k0 + 64 < kend) stage(cur ^ 1, k0 + 64);   // prefetch in flight
        const short* As = &S[cur][0][0];
        const short* Bs = &S[cur][1][0];
        #pragma unroll
        for (int ks = 0; ks < 2; ++ks) {
            bf16x8 af[4], bfr[4];
            #pragma unroll
            for (int mt = 0; mt < 4; ++mt) {
                int ar = wm * 64 + mt * 16 + lr;
                af[mt] = *(const bf16x8*)&As[ar * 64 + (((ks*4 + q) ^ (ar & 7)) << 3)];
            }
            #pragma unroll
            for (int nt = 0; nt < 4; ++nt) {
                int br = wn * 64 + nt * 16 + lr;
                bfr[nt] = *(const bf16x8*)&Bs[br * 64 + (((ks*4 + q) ^ (br & 7)) << 3)];
            }
            #pragma unroll
            for (int mt = 0; mt < 4; ++mt)
                #pragma unroll
                for (int nt = 0; nt < 4; ++nt)
                    acc[mt][nt] = __builtin_amdgcn_mfma_f32_16x16x32_bf16(
                        af[mt], bfr[nt], acc[mt][nt], 0, 0, 0);
        }
        __syncthreads();                       // drains prefetch vmcnt + reads
        cur ^= 1;
    }

    if (mode == 0) {
        #pragma unroll
        for (int mt = 0; mt < 4; ++mt)
            #pragma unroll
            for (int nt = 0; nt < 4; ++nt)
                #pragma unroll
                for (int r = 0; r < 4; ++r) {
                    int m = m0 + wm * 64 + mt * 16 + q * 4 + r;
                    int n = n0 + wn * 64 + nt * 16 + lr;
                    float v = acc[mt][nt][r] + bias[n];
                    ((float*)out0)[(size_t)m * 256 + n] = v > 0.f ? v : 0.f;
                }
    } else if (mode == 2) {
        float* Mo = (float*)out0 + (size_t)sim * 65536;
        #pragma unroll
        for (int mt = 0; mt < 4; ++mt)
            #pragma unroll
            for (int nt = 0; nt < 4; ++nt)
                #pragma unroll
                for (int r = 0; r < 4; ++r) {
                    int m = m0 + wm * 64 + mt * 16 + q * 4 + r;
                    int n = n0 + wn * 64 + nt * 16 + lr;
                    atomicAdd(&Mo[(size_t)m * 256 + n], acc[mt][nt][r] * scale);
                }
    } else {
        // mode 1: restage e=relu(acc+bias) as Hs (row-major) + Ts (transposed,
        // pre-swizzled) over the two LDS buffers (free after last barrier).
        short* Hs = &S[0][0][0];               // [128][128] row-major
        short* Ts = &S[1][0][0];               // [128][128] n-major, swizzled
        #pragma unroll
        for (int mt = 0; mt < 4; ++mt)
            #pragma unroll
            for (int nt = 0; nt < 4; ++nt) {
                int n_loc = wn * 64 + nt * 16 + lr;
                float bb = bias[n0 + n_loc];
                short vb[4];
                #pragma unroll
                for (int r = 0; r < 4; ++r) {
                    int m_loc = wm * 64 + mt * 16 + q * 4 + r;
                    float v = acc[mt][nt][r] + bb;
                    vb[r] = f2bf(v > 0.f ? v : 0.f);
                    Hs[m_loc * 128 + n_loc] = vb[r];
                }
                int gm = wm * 8 + mt * 2 + (q >> 1);   // m-granule 0..15
                short4v pk = { vb[0], vb[1], vb[2], vb[3] };
                *(short4v*)&Ts[n_loc * 128 + ((gm >> 3) << 6)
                               + (((gm & 7) ^ (n_loc & 7)) << 3) + ((q & 1) << 2)] = pk;
            }
        __syncthreads();
        short* et = (short*)(sim ? out1 : out0);
        const int cb = 256 + sim * 256 + n0;   // h column-block base
        for (int i = t; i < 2048; i += 256) {  // h: 128 rows x 16 granules
            int ml = i >> 4, g = i & 15;
            bf16x8 hv = *(const bf16x8*)&Hs[ml * 128 + g * 8];
            *(bf16x8*)(hout + (size_t)(m0 + ml) * ldh + cb + ((g >> 3) << 6)
                       + (((g & 7) ^ (ml & 7)) << 3)) = hv;
        }
        for (int i = t; i < 2048; i += 256) {  // et: Ts slot s -> global slot s
            int nl = i >> 4, s = i & 15;
            bf16x8 tv = *(const bf16x8*)&Ts[nl * 128 + s * 8];
            *(bf16x8*)(et + (size_t)(n0 + nl) * 8192 + m0 + s * 8) = tv;
        }
    }
}

// ---------------------------------------------------------- gemm_small_n
// N_sim^T[n,c] = sum_d Wtoh[n, sim*256+d] * M_sim[c,d]   (K=256)
// A = Wtoh (bf16 swizzled, DMA);  B = M fp32 -> bf16 VGPR-staged into Bs.
// Output written bf16 granule-swizzled into Bt4 cols 256+sim*256+c0.
__global__ __launch_bounds__(256, 1)
void gemm_small_n(const short* __restrict__ Wtoh, const float* __restrict__ M,
                  short* __restrict__ Bt4)
{
    const int sim = blockIdx.z;
    const int n0 = blockIdx.x * 64, c0 = blockIdx.y * 64;
    const int t = threadIdx.x;
    const int w = t >> 6, l = t & 63, lr = l & 15, q = l >> 4;
    const int wub = t & ~63;
    const float* Ms = M + (size_t)sim * 65536;

    __shared__ __attribute__((aligned(16))) short As[64 * 64];
    __shared__ __attribute__((aligned(16))) short Bs[64 * 64];

    f32x4 acc[4];
    #pragma unroll
    for (int i = 0; i < 4; ++i) acc[i] = f32x4{0.f, 0.f, 0.f, 0.f};

    for (int k0 = 0; k0 < 256; k0 += 64) {
        __syncthreads();
        #pragma unroll
        for (int it = 0; it < 2; ++it) {
            int idx = it * 256 + t;
            int r = idx >> 3, s = idx & 7;
            cp16_async((const char*)(Wtoh + (size_t)(n0 + r) * 512 + sim * 256 + k0) + s * 16,
                       (char*)As + (size_t)(it * 256 + wub) * 16);
        }
        for (int i = t; i < 512; i += 256) {      // B: M fp32 -> bf16 swizzled
            int r = i >> 3, g = i & 7;
            const float* mp = Ms + (size_t)(c0 + r) * 256 + k0 + g * 8;
            f32x4 va = *(const f32x4*)mp;
            f32x4 vb = *(const f32x4*)(mp + 4);
            bf16x8 pk;
            pk[0] = f2bf(va[0]); pk[1] = f2bf(va[1]);
            pk[2] = f2bf(va[2]); pk[3] = f2bf(va[3]);
            pk[4] = f2bf(vb[0]); pk[5] = f2bf(vb[1]);
            pk[6] = f2bf(vb[2]); pk[7] = f2bf(vb[3]);
            *(bf16x8*)&Bs[r * 64 + ((g ^ (r & 7)) << 3)] = pk;
        }
        __syncthreads();
        #pragma unroll
        for (int ks = 0; ks < 2; ++ks) {
            int arow = w * 16 + lr;
            bf16x8 af = *(const bf16x8*)&As[arow * 64 + (((ks*4 + q) ^ (arow & 7)) << 3)];
            #pragma unroll
            for (int nt = 0; nt < 4; ++nt) {
                int brow = nt * 16 + lr;
                bf16x8 bfg = *(const bf16x8*)&Bs[brow * 64 + (((ks*4 + q) ^ (brow & 7)) << 3)];
                acc[nt] = __builtin_amdgcn_mfma_f32_16x16x32_bf16(af, bfg, acc[nt], 0, 0, 0);
            }
        }
    }
    // epilogue: restage bf16 tile, write swizzled granules into Bt4
    __syncthreads();
    #pragma unroll
    for (int nt = 0; nt < 4; ++nt)
        #pragma unroll
        for (int r = 0; r < 4; ++r)
            As[(w * 16 + q * 4 + r) * 64 + nt * 16 + lr] = f2bf(acc[nt][r]);
    __syncthreads();
    const int cb = 256 + sim * 256 + c0;
    for (int i = t; i < 512; i += 256) {
        int rl = i >> 3, g = i & 7;
        bf16x8 v = *(const bf16x8*)&As[rl * 64 + g * 8];
        int m = n0 + rl;
        int slot = g ^ (m & 7);
        *(bf16x8*)(Bt4 + (size_t)m * 768 + cb + slot * 8) = v;
    }
}

// ---------------------------------------------------------------- launch
extern "C" void kernel_launch(void* const* d_in, const int* in_sizes, int n_in,
                              void* d_out, int out_size, void* d_ws, size_t ws_size,
                              hipStream_t stream)
{
    const float* edge_x = (const float*)d_in[0];
    const float* W1 = (const float*)d_in[1];
    const float* b1 = (const float*)d_in[2];
    const float* W2 = (const float*)d_in[3];
    const float* b2 = (const float*)d_in[4];
    const float* Wo = (const float*)d_in[5];
    const float* bo = (const float*)d_in[6];

    // workspace layout (26,607,616 B total; R14 proved this fits)
    char* ws = (char*)d_ws;
    short* h    = (short*)ws;                    // [8192][768] bf16 swz  12,582,912
    short* Xt   = (short*)(ws + 12582912);       // [256][8192] bf16 swz   4,194,304
    short* e1t  = (short*)(ws + 16777216);       // [256][8192] bf16 swz   4,194,304
    short* e2t  = (short*)(ws + 20971520);       // [256][8192] bf16 swz   4,194,304
    short* Wt1  = (short*)(ws + 25165824);       // [256][256]  bf16 swz     131,072
    short* Wt2  = (short*)(ws + 25296896);       // [256][256]  bf16 swz     131,072
    short* Wtoh = (short*)(ws + 25427968);       // [256][512]  bf16 swz     262,144
    short* Bt4  = (short*)(ws + 25690112);       // [256][768]  bf16 swz     393,216
    float* M    = (float*)(ws + 26083328);       // [2][256][256] fp32       524,288

    prep_all<<<dim3(256, 10), dim3(32, 8), 0, stream>>>(
        edge_x, h, 768, Xt, W1, W2, Wo, Wt1, Wt2, Wtoh, Bt4, M);

    // e1/e2 = relu(X@Wi+bi): -> h cols 256:768 (swz) + e1t/e2t transposed
    gemm128<<<dim3(64, 2, 2), 256, 0, stream>>>(
        h, h, 768, Wt1, Wt2, 256, 256, b1, b2, e1t, e2t, h, 768, 1, 0.f);

    // M_i = (e_i^T @ X)/256  (split-K 16, atomic fp32; z = split*2+sim)
    gemm128<<<dim3(2, 2, 32), 256, 0, stream>>>(
        e1t, e2t, 8192, Xt, Xt, 8192, 8192, nullptr, nullptr, M, nullptr,
        nullptr, 0, 2, 1.0f / 256.0f);

    // N_i^T = Wo_i^T @ M_i^T -> Bt4 cols 256:768
    gemm_small_n<<<dim3(4, 4, 2), 256, 0, stream>>>(Wtoh, M, Bt4);

    // out = relu(h @ Bt4^T + bo),  K=768
    gemm128<<<dim3(64, 2, 1), 256, 0, stream>>>(
        h, h, 768, Bt4, Bt4, 768, 768, bo, bo, (float*)d_out, nullptr,
        nullptr, 0, 0, 0.f);
}

// Round 6
// 114.052 us; speedup vs baseline: 1.0091x; 1.0091x over previous
//
#include <hip/hip_runtime.h>
#include <hip/hip_bf16.h>

// MPNN fused pipeline, R17b: byte-equivalent resubmission of R17 (container
// failed twice with no diagnostics; same signature as R15's infra flake,
// whose identical resubmission passed; kernel re-audited for OOB/deadlock/
// alignment — clean).  Bisection round after R16's absmax failure.
// Keeps the G-route algebra (N_i = (1/256) G_i^T e_i, G_i = X@Wo_i; kills
// gemm_small_n's GEMM and Xt) but REVERTS the final stage to R15b's proven
// form: final GEMM K=768 reading Bt4=[Wo0^T | N1^T | N2^T] via pure DMA,
// plain bias+relu fp32 epilogue. N^T materialized into Bt4 by a tiny
// convert kernel using gemm_small_n's proven swizzled-store pattern.
// Removed vs R16 (bisected out): mode 4 partial, RMW epilogue, fused
// fp32->bf16 B staging inside the dbuf K-loop.
// Pipeline (5 dispatches): prep -> job0 (grid 64x2x4: e1,e2,G1,G2) ->
//   job1 (Nacc split-K atomics, R15b-proven mechanics) -> convert_n ->
//   final (R15b-exact mode 0).

typedef short bf16x8  __attribute__((ext_vector_type(8)));
typedef short short4v __attribute__((ext_vector_type(4)));
typedef float f32x4   __attribute__((ext_vector_type(4)));

__device__ inline short f2bf(float x) {                // fp32 -> bf16 RNE
    unsigned u = __builtin_bit_cast(unsigned, x);
    return (short)((u + 0x7fffu + ((u >> 16) & 1u)) >> 16);
}
__device__ inline float bf2f(short b) {
    return __builtin_bit_cast(float, (unsigned)((unsigned short)b) << 16);
}
__device__ inline void cp16_async(const char* g, char* l) {
    __builtin_amdgcn_global_load_lds(
        (const __attribute__((address_space(1))) unsigned int*)g,
        (__attribute__((address_space(3))) unsigned int*)l, 16, 0, 0);
}

// ------------------------------------------------------------------ prep_all
// grid (256,10), block (32,8):
//   y<8    : edge_x fp32 -> bf16 h[:,0:256] (granule-swizzled).
//   y>=8   : tw<64   -> W1 tile -> Wt1 (swizzled [n][k], ld 256)
//            tw<128  -> W2 tile -> Wt2
//            tw<320  -> Wo g=0 -> Bt4[:,0:256] (ld 768, R15b-proven path)
//                       Wo g=1 -> Wto1 (ld 256);  g=2 -> Wto2
//            tw>=320 -> zero Nacc (2*256*256 fp32) for job1 atomics.
__global__ void prep_all(const float* __restrict__ X, short* __restrict__ h,
                         const float* __restrict__ W1, const float* __restrict__ W2,
                         const float* __restrict__ Wo,
                         short* __restrict__ Wt1, short* __restrict__ Wt2,
                         short* __restrict__ Wto1, short* __restrict__ Wto2,
                         short* __restrict__ Bt4, float* __restrict__ Nacc)
{
    __shared__ short tile[32][33];
    const int tx = threadIdx.x, ty = threadIdx.y;      // 32 x 8
    if (blockIdx.y < 8) {
        const int r0 = blockIdx.x * 32, c0 = blockIdx.y * 32;
        #pragma unroll
        for (int i = 0; i < 4; ++i) {
            int row = ty + i * 8;
            short b = f2bf(X[(size_t)(r0 + row) * 256 + c0 + tx]);
            int slot = ((((c0 & 32) + tx) >> 3) ^ ((r0 + row) & 7));
            h[(size_t)(r0 + row) * 768 + (c0 & ~63) + slot * 8 + (tx & 7)] = b;
        }
        return;
    }
    int tw = (blockIdx.y - 8) * 256 + blockIdx.x;
    if (tw >= 320) {                               // zero Nacc with idle blocks
        int i0 = (tw - 320) * 256 + ty * 32 + tx;
        for (int i = i0; i < 131072; i += 49152) Nacc[i] = 0.f;
        return;
    }
    const float* src; short* dst; int ldwt, dk0, kx, ny;
    if (tw < 64)       { src = W1; dst = Wt1; ldwt = 256;
                         kx = tw >> 3; ny = tw & 7; dk0 = kx * 32; }
    else if (tw < 128) { int u = tw - 64; src = W2; dst = Wt2; ldwt = 256;
                         kx = u >> 3; ny = u & 7; dk0 = kx * 32; }
    else               { int u = tw - 128; int g = u >> 6; int rem = u & 63;
                         kx = rem >> 3; ny = rem & 7;
                         src = Wo + (size_t)g * 65536;
                         if (g == 0) { dst = Bt4; ldwt = 768; dk0 = kx * 32; }
                         else        { dst = (g == 1) ? Wto1 : Wto2;
                                       ldwt = 256; dk0 = kx * 32; } }
    const int k0l = kx * 32, n0 = ny * 32;
    #pragma unroll
    for (int i = 0; i < 4; ++i) {
        int row = ty + i * 8;
        tile[row][tx] = f2bf(src[(size_t)(k0l + row) * 256 + n0 + tx]);
    }
    __syncthreads();
    #pragma unroll
    for (int i = 0; i < 4; ++i) {
        int row = ty + i * 8;
        int n = n0 + row;
        int slot = ((((dk0 & 32) + tx) >> 3) ^ (n & 7));
        dst[(size_t)n * ldwt + (dk0 & ~63) + slot * 8 + (tx & 7)] = tile[tx][row];
    }
}

// ------------------------------------------------------------------ gemm_all
// 128x128-tile, BK=64, 4 waves 2x2, double-buffered global_load_lds staging
// (core identical to R15b's gemm128, which passed with absmax 0.5).
// job 0 (grid 64,2,4):
//   z<2 : e_z = relu(h[:,0:256]@W_z + b_z)  -> h cols 256+z*256 (swz) + e_zt
//   z<4 : G_s = h[:,0:256]@Wo_{s+1}         -> G_st (transposed, swz) only
// job 1 (grid 2,2,32): Nacc[sim] += (G_simt @ e_simt^T)/256  split-K atomics
// job 2 (grid 64,2,1): out = relu(h @ Bt4^T + bo), K=768, pure DMA (R15b).
__global__ __launch_bounds__(256, 1)
void gemm_all(int job, short* __restrict__ h,
              const short* __restrict__ Wt1, const short* __restrict__ Wt2,
              const short* __restrict__ Wto1, const short* __restrict__ Wto2,
              const short* __restrict__ Bt4,
              const float* __restrict__ b1, const float* __restrict__ b2,
              const float* __restrict__ bo,
              short* __restrict__ e1t, short* __restrict__ e2t,
              short* __restrict__ G1t, short* __restrict__ G2t,
              float* __restrict__ Nacc, float* __restrict__ outf)
{
    const int z = blockIdx.z;
    int mode, sim = 0, kbeg = 0, kend, lda, ldb;
    const short *Ap, *Bp;
    const float* bias = nullptr;
    short* et = nullptr;
    if (job == 0) {
        Ap = h; lda = 768; kend = 256; ldb = 256;
        if (z < 2) { mode = 1; sim = z;     Bp = z ? Wt2 : Wt1;
                     bias = z ? b2 : b1;    et = z ? e2t : e1t; }
        else       { mode = 3; sim = z - 2; Bp = sim ? Wto2 : Wto1;
                     et = sim ? G2t : G1t; }
    } else if (job == 1) {
        mode = 2; sim = z & 1;
        kbeg = (z >> 1) * 512; kend = kbeg + 512;
        Ap = sim ? G2t : G1t; lda = 8192;
        Bp = sim ? e2t : e1t; ldb = 8192;
    } else {
        mode = 0; Ap = h; lda = 768; kend = 768;
        Bp = Bt4; ldb = 768; bias = bo;
    }

    const int m0 = blockIdx.x * 128, n0 = blockIdx.y * 128;
    const int t = threadIdx.x;
    const int w = t >> 6, l = t & 63, lr = l & 15, q = l >> 4;
    const int wm = w >> 1, wn = w & 1;         // wave quadrant (2x2)
    const int wub = t & ~63;                   // wave-uniform thread base

    __shared__ __attribute__((aligned(16))) short S[2][2][128 * 64]; // 64 KB

    f32x4 acc[4][4];
    #pragma unroll
    for (int i = 0; i < 4; ++i)
        #pragma unroll
        for (int j = 0; j < 4; ++j) acc[i][j] = f32x4{0.f, 0.f, 0.f, 0.f};

    auto stage = [&](int buf, int k0) {
        #pragma unroll
        for (int it = 0; it < 4; ++it) {       // A: 128 rows x 8 granules, DMA
            int idx = it * 256 + t;
            int r = idx >> 3, s = idx & 7;
            cp16_async((const char*)(Ap + (size_t)(m0 + r) * lda + k0) + s * 16,
                       (char*)&S[buf][0][0] + (size_t)(it * 256 + wub) * 16);
        }
        #pragma unroll
        for (int it = 0; it < 4; ++it) {       // B: 128 rows x 8 granules, DMA
            int idx = it * 256 + t;
            int r = idx >> 3, s = idx & 7;
            cp16_async((const char*)(Bp + (size_t)(n0 + r) * ldb + k0) + s * 16,
                       (char*)&S[buf][1][0] + (size_t)(it * 256 + wub) * 16);
        }
    };

    stage(0, kbeg);
    __syncthreads();                           // full drain: buf0 ready
    int cur = 0;
    for (int k0 = kbeg; k0 < kend; k0 += 64) {
        if (k0 + 64 < kend) stage(cur ^ 1, k0 + 64);   // prefetch in flight
        const short* As = &S[cur][0][0];
        const short* Bs = &S[cur][1][0];
        #pragma unroll
        for (int ks = 0; ks < 2; ++ks) {
            bf16x8 af[4], bfr[4];
            #pragma unroll
            for (int mt = 0; mt < 4; ++mt) {
                int ar = wm * 64 + mt * 16 + lr;
                af[mt] = *(const bf16x8*)&As[ar * 64 + (((ks*4 + q) ^ (ar & 7)) << 3)];
            }
            #pragma unroll
            for (int nt = 0; nt < 4; ++nt) {
                int br = wn * 64 + nt * 16 + lr;
                bfr[nt] = *(const bf16x8*)&Bs[br * 64 + (((ks*4 + q) ^ (br & 7)) << 3)];
            }
            #pragma unroll
            for (int mt = 0; mt < 4; ++mt)
                #pragma unroll
                for (int nt = 0; nt < 4; ++nt)
                    acc[mt][nt] = __builtin_amdgcn_mfma_f32_16x16x32_bf16(
                        af[mt], bfr[nt], acc[mt][nt], 0, 0, 0);
        }
        __syncthreads();                       // drains prefetch vmcnt + reads
        cur ^= 1;
    }

    if (mode == 0) {                           // final: bias + relu (R15b)
        #pragma unroll
        for (int mt = 0; mt < 4; ++mt)
            #pragma unroll
            for (int nt = 0; nt < 4; ++nt)
                #pragma unroll
                for (int r = 0; r < 4; ++r) {
                    int m = m0 + wm * 64 + mt * 16 + q * 4 + r;
                    int n = n0 + wn * 64 + nt * 16 + lr;
                    float v = acc[mt][nt][r] + bias[n];
                    outf[(size_t)m * 256 + n] = v > 0.f ? v : 0.f;
                }
    } else if (mode == 2) {                    // N split-K atomics
        float* Mo = Nacc + (size_t)sim * 65536;
        #pragma unroll
        for (int mt = 0; mt < 4; ++mt)
            #pragma unroll
            for (int nt = 0; nt < 4; ++nt)
                #pragma unroll
                for (int r = 0; r < 4; ++r) {
                    int m = m0 + wm * 64 + mt * 16 + q * 4 + r;
                    int n = n0 + wn * 64 + nt * 16 + lr;
                    atomicAdd(&Mo[(size_t)m * 256 + n],
                              acc[mt][nt][r] * (1.0f / 256.0f));
                }
    } else {
        // mode 1/3: restage (relu(acc+bias) | acc) as Hs (row-major, mode 1
        // only) + Ts (transposed, pre-swizzled) in the now-free LDS buffers.
        short* Hs = &S[0][0][0];               // [128][128] row-major
        short* Ts = &S[1][0][0];               // [128][128] n-major, swizzled
        #pragma unroll
        for (int mt = 0; mt < 4; ++mt)
            #pragma unroll
            for (int nt = 0; nt < 4; ++nt) {
                int n_loc = wn * 64 + nt * 16 + lr;
                float bb = (mode == 1) ? bias[n0 + n_loc] : 0.f;
                short vb[4];
                #pragma unroll
                for (int r = 0; r < 4; ++r) {
                    float v = acc[mt][nt][r] + bb;
                    if (mode == 1) v = v > 0.f ? v : 0.f;
                    vb[r] = f2bf(v);
                    if (mode == 1) {
                        int m_loc = wm * 64 + mt * 16 + q * 4 + r;
                        Hs[m_loc * 128 + n_loc] = vb[r];
                    }
                }
                int gm = wm * 8 + mt * 2 + (q >> 1);   // m-granule 0..15
                short4v pk = { vb[0], vb[1], vb[2], vb[3] };
                *(short4v*)&Ts[n_loc * 128 + ((gm >> 3) << 6)
                               + (((gm & 7) ^ (n_loc & 7)) << 3) + ((q & 1) << 2)] = pk;
            }
        __syncthreads();
        if (mode == 1) {
            const int cb = 256 + sim * 256 + n0;   // h column-block base
            for (int i = t; i < 2048; i += 256) {  // h: 128 rows x 16 granules
                int ml = i >> 4, g = i & 15;
                bf16x8 hv = *(const bf16x8*)&Hs[ml * 128 + g * 8];
                *(bf16x8*)(h + (size_t)(m0 + ml) * 768 + cb + ((g >> 3) << 6)
                           + (((g & 7) ^ (ml & 7)) << 3)) = hv;
            }
        }
        for (int i = t; i < 2048; i += 256) {      // et/Gt: slot s -> global s
            int nl = i >> 4, s = i & 15;
            bf16x8 tv = *(const bf16x8*)&Ts[nl * 128 + s * 8];
            *(bf16x8*)(et + (size_t)(n0 + nl) * 8192 + m0 + s * 8) = tv;
        }
    }
}

// ---------------------------------------------------------- convert_n
// Bt4[n][256+sim*256+c] (bf16, granule-swizzled) = Nacc[sim][n][c].
// Store pattern identical to gemm_small_n's proven epilogue.
// grid (64), block (256): one 8-col granule per thread.
__global__ void convert_n(const float* __restrict__ Nacc, short* __restrict__ Bt4)
{
    int gid = blockIdx.x * 256 + threadIdx.x;      // 0..16383
    int sim = gid >> 13, rem = gid & 8191;
    int n = rem >> 5, g = rem & 31;                // row, granule (c = g*8)
    const float* np = Nacc + (size_t)sim * 65536 + (size_t)n * 256 + g * 8;
    f32x4 va = *(const f32x4*)np;
    f32x4 vb = *(const f32x4*)(np + 4);
    bf16x8 pk;
    pk[0] = f2bf(va[0]); pk[1] = f2bf(va[1]);
    pk[2] = f2bf(va[2]); pk[3] = f2bf(va[3]);
    pk[4] = f2bf(vb[0]); pk[5] = f2bf(vb[1]);
    pk[6] = f2bf(vb[2]); pk[7] = f2bf(vb[3]);
    int k = 256 + sim * 256 + g * 8;               // global column
    int slot = (g & 7) ^ (n & 7);
    *(bf16x8*)(Bt4 + (size_t)n * 768 + (k & ~63) + slot * 8) = pk;
}

// ---------------------------------------------------------------- launch
extern "C" void kernel_launch(void* const* d_in, const int* in_sizes, int n_in,
                              void* d_out, int out_size, void* d_ws, size_t ws_size,
                              hipStream_t stream)
{
    const float* edge_x = (const float*)d_in[0];
    const float* W1 = (const float*)d_in[1];
    const float* b1 = (const float*)d_in[2];
    const float* W2 = (const float*)d_in[3];
    const float* b2 = (const float*)d_in[4];
    const float* Wo = (const float*)d_in[5];
    const float* bo = (const float*)d_in[6];

    // workspace layout (~31 MB; poison fill shows ws >= 256 MB)
    char* ws = (char*)d_ws;
    short* h    = (short*)ws;                    // [8192][768] bf16 swz  12,582,912
    short* e1t  = (short*)(ws + 12582912);       // [256][8192] bf16 swz   4,194,304
    short* e2t  = (short*)(ws + 16777216);       // [256][8192] bf16 swz   4,194,304
    short* G1t  = (short*)(ws + 20971520);       // [256][8192] bf16 swz   4,194,304
    short* G2t  = (short*)(ws + 25165824);       // [256][8192] bf16 swz   4,194,304
    short* Wt1  = (short*)(ws + 29360128);       // [256][256]  bf16 swz     131,072
    short* Wt2  = (short*)(ws + 29491200);       // [256][256]  bf16 swz     131,072
    short* Wto1 = (short*)(ws + 29622272);       // [256][256]  bf16 swz     131,072
    short* Wto2 = (short*)(ws + 29753344);       // [256][256]  bf16 swz     131,072
    short* Bt4  = (short*)(ws + 29884416);       // [256][768]  bf16 swz     393,216
    float* Nacc = (float*)(ws + 30277632);       // [2][256][256] fp32       524,288

    float* out = (float*)d_out;

    prep_all<<<dim3(256, 10), dim3(32, 8), 0, stream>>>(
        edge_x, h, W1, W2, Wo, Wt1, Wt2, Wto1, Wto2, Bt4, Nacc);

    // z=0,1: e_i -> h cols + e_it ; z=2,3: G_i -> G_it
    gemm_all<<<dim3(64, 2, 4), 256, 0, stream>>>(
        0, h, Wt1, Wt2, Wto1, Wto2, Bt4, b1, b2, bo,
        e1t, e2t, G1t, G2t, Nacc, out);

    // Nacc[sim] = (G_sim^T e_sim)/256  (split-K 16, atomics)
    gemm_all<<<dim3(2, 2, 32), 256, 0, stream>>>(
        1, h, Wt1, Wt2, Wto1, Wto2, Bt4, b1, b2, bo,
        e1t, e2t, G1t, G2t, Nacc, out);

    // N^T -> Bt4 cols 256:768 (bf16, swizzled)
    convert_n<<<dim3(64), 256, 0, stream>>>(Nacc, Bt4);

    // out = relu(h @ Bt4^T + bo),  K=768  (R15b-exact final)
    gemm_all<<<dim3(64, 2, 1), 256, 0, stream>>>(
        2, h, Wt1, Wt2, Wto1, Wto2, Bt4, b1, b2, bo,
        e1t, e2t, G1t, G2t, Nacc, out);
}